// Round 6
// baseline (325.548 us; speedup 1.0000x reference)
//
#include <hip/hip_runtime.h>
#include <math.h>

using bf16x8 = __attribute__((ext_vector_type(8))) short;
using f32x4  = __attribute__((ext_vector_type(4))) float;
using u16x8  = __attribute__((ext_vector_type(8))) unsigned short;
using u16x4  = __attribute__((ext_vector_type(4))) unsigned short;

constexpr int Bb = 4, Tt = 2048, Ee = 1024, Hh = 16;
constexpr int Mm = Bb * Tt;   // 8192
constexpr int E3 = 3 * Ee;    // 3072

__device__ __forceinline__ unsigned short f2bf(float f) {
  union { float f; unsigned int u; } c; c.f = f;
  unsigned int u = c.u;
  u += 0x7fffu + ((u >> 16) & 1u);   // RNE
  return (unsigned short)(u >> 16);
}

__device__ __forceinline__ f32x4 mfma16(bf16x8 a, bf16x8 b, f32x4 c) {
  return __builtin_amdgcn_mfma_f32_16x16x32_bf16(a, b, c, 0, 0, 0);
}

__device__ __forceinline__ void gload_lds16(const unsigned short* g, unsigned short* l) {
  __builtin_amdgcn_global_load_lds(
      (const __attribute__((address_space(1))) unsigned int*)g,
      (__attribute__((address_space(3))) unsigned int*)l, 16, 0, 0);
}

// ---------------------------------------------------------------------------
// fused fp32 -> bf16 conversion for all three inputs (one launch)
// ---------------------------------------------------------------------------
__global__ void cvt_all(const float* __restrict__ q, const float* __restrict__ iw,
                        const float* __restrict__ ow, unsigned short* __restrict__ qb,
                        unsigned short* __restrict__ wib, unsigned short* __restrict__ wob) {
  constexpr int nQ = Mm * Ee / 8, nI = E3 * Ee / 8, nO = Ee * Ee / 8;
  int i = blockIdx.x * 256 + threadIdx.x;
  const float* in; unsigned short* out;
  if (i < nQ) { in = q; out = qb; }
  else if (i < nQ + nI) { in = iw; out = wib; i -= nQ; }
  else if (i < nQ + nI + nO) { in = ow; out = wob; i -= nQ + nI; }
  else return;
  const float4* p = (const float4*)in + (size_t)i * 2;
  const float4 a = p[0], b = p[1];
  u16x8 r = { f2bf(a.x), f2bf(a.y), f2bf(a.z), f2bf(a.w),
              f2bf(b.x), f2bf(b.y), f2bf(b.z), f2bf(b.w) };
  *(u16x8*)(out + (size_t)i * 8) = r;
}

// ---------------------------------------------------------------------------
// C[M,N] = A[M,K] * Bw[N,K]^T + bias  (bf16 MFMA, m97-style)
// QSCALE: cols<1024 (q part) scaled by log2(e)/8 after bias (exp2 trick).
// ---------------------------------------------------------------------------
template <bool OUT_BF16, bool QSCALE>
__global__ __launch_bounds__(256, 2)
void gemm_bt(const unsigned short* __restrict__ A, const unsigned short* __restrict__ Bw,
             const float* __restrict__ bias, void* __restrict__ Cout, int N, int K) {
  __shared__ alignas(16) unsigned short As[128 * 32];
  __shared__ alignas(16) unsigned short Bs[128 * 32];
  const int tid = threadIdx.x;
  const int wave = tid >> 6, lane = tid & 63;
  const int l15 = lane & 15, quad = lane >> 4;
  const int wr = wave >> 1, wc = wave & 1;
  const int row0 = blockIdx.y * 128, col0 = blockIdx.x * 128;
  const int srow = lane >> 2, sslot = lane & 3;

  f32x4 acc[4][4];
#pragma unroll
  for (int i = 0; i < 4; ++i)
#pragma unroll
    for (int j = 0; j < 4; ++j) acc[i][j] = f32x4{0.f, 0.f, 0.f, 0.f};

  for (int k0 = 0; k0 < K; k0 += 32) {
#pragma unroll
    for (int t = 0; t < 2; ++t) {
      const int rA = wave * 32 + t * 16 + srow;          // 0..127
      const int g = sslot ^ ((rA >> 1) & 3);             // swizzled global chunk
      gload_lds16(A  + (size_t)(row0 + rA) * K + k0 + g * 8, &As[(wave * 32 + t * 16) * 32]);
      gload_lds16(Bw + (size_t)(col0 + rA) * K + k0 + g * 8, &Bs[(wave * 32 + t * 16) * 32]);
    }
    __syncthreads();

    bf16x8 af[4], bfr[4];
#pragma unroll
    for (int mi = 0; mi < 4; ++mi) {
      const int m = wr * 64 + mi * 16 + l15;
      af[mi] = *(const bf16x8*)&As[m * 32 + (quad ^ ((m >> 1) & 3)) * 8];
    }
#pragma unroll
    for (int ni = 0; ni < 4; ++ni) {
      const int n = wc * 64 + ni * 16 + l15;
      bfr[ni] = *(const bf16x8*)&Bs[n * 32 + (quad ^ ((n >> 1) & 3)) * 8];
    }
#pragma unroll
    for (int mi = 0; mi < 4; ++mi)
#pragma unroll
      for (int ni = 0; ni < 4; ++ni) acc[mi][ni] = mfma16(af[mi], bfr[ni], acc[mi][ni]);
    __syncthreads();
  }

#pragma unroll
  for (int mi = 0; mi < 4; ++mi)
#pragma unroll
    for (int ni = 0; ni < 4; ++ni) {
      const int col = col0 + wc * 64 + ni * 16 + l15;
      const float bv = bias[col];
      const float scale = (QSCALE && col < 1024) ? 0.18033688f : 1.0f;  // log2(e)/8
#pragma unroll
      for (int r = 0; r < 4; ++r) {
        const int row = row0 + wr * 64 + mi * 16 + quad * 4 + r;
        float v = (acc[mi][ni][r] + bv) * scale;
        if (OUT_BF16)
          ((unsigned short*)Cout)[(size_t)row * N + col] = f2bf(v);
        else
          ((float*)Cout)[(size_t)row * N + col] = v;
      }
    }
}

// ---------------------------------------------------------------------------
// V transpose: vt[b][h][d][t] <- qkv v-part [b][t][2048 + h*64 + d]
// ---------------------------------------------------------------------------
__global__ __launch_bounds__(256, 2)
void transpose_v(const unsigned short* __restrict__ qkv, unsigned short* __restrict__ vt) {
  __shared__ unsigned short L[128][66];
  const int tid = threadIdx.x;
  const int bh = blockIdx.x, b = bh >> 4, h = bh & 15;
  const int t0 = blockIdx.y * 128;
#pragma unroll
  for (int p = 0; p < 8; ++p) {
    const int tl = p * 16 + (tid >> 4);
    const int d = (tid & 15) * 4;
    *(u16x4*)&L[tl][d] = *(const u16x4*)(qkv + (size_t)(b * Tt + t0 + tl) * E3 + 2 * Ee + h * 64 + d);
  }
  __syncthreads();
#pragma unroll
  for (int p = 0; p < 8; ++p) {
    const int dw = (tid >> 5) * 8 + p;
    const int tw = (tid & 31) * 4;
    u16x4 w = { L[tw][dw], L[tw + 1][dw], L[tw + 2][dw], L[tw + 3][dw] };
    *(u16x4*)(vt + ((size_t)bh * 64 + dw) * Tt + t0 + tw) = w;
  }
}

// ---------------------------------------------------------------------------
// Fused attention: KEY-SPLIT x2 + software-pipelined body, NO register cap.
// Block = 4 waves = 2 q-tiles(64) x 2 k-halves(1024); grid 64 x 16 = 1024
// blocks -> 4 blocks/CU (LDS 40960x4 = 160 KB exactly), 4 waves/SIMD if
// VGPR<=128. Wave: S^T = MFMA(A=K,B=Q) -> exp2 -> perm-pack -> swizzled
// per-wave-private LDS P -> PV (A=P via ds_read_b128, B=V^T from global);
// l = P.ones MFMA. kb/vb reloaded at WAR-safe points; last iter peeled.
// k-half partials (O,l) combine by addition through LDS (no running max).
// ---------------------------------------------------------------------------
__global__ __launch_bounds__(256, 2)
void attn_mfma5(const unsigned short* __restrict__ qkv,
                const unsigned short* __restrict__ vt,
                unsigned short* __restrict__ ctx) {
  // k-loop: 4 x 8 KB per-wave P slabs; epilogue: 2 x 20480 B exchange areas
  __shared__ alignas(16) char lds[40960];
  const int tid = threadIdx.x;
  const int wave = tid >> 6, lane = tid & 63;
  const int l15 = lane & 15, quad = lane >> 4;
  const int pair = wave >> 1, kh = wave & 1;
  const int bh = blockIdx.x, b = bh >> 4, h = bh & 15;
  const int q0 = blockIdx.y * 128 + pair * 64;
  unsigned short* const ps = (unsigned short*)lds + wave * 4096;
  const int swz = l15 & 14;

  // Q fragments (B operand): q = q0 + qi*16 + l15, d = kf*32 + quad*8
  bf16x8 qa[4][2];
#pragma unroll
  for (int qi = 0; qi < 4; ++qi)
#pragma unroll
    for (int kf = 0; kf < 2; ++kf)
      qa[qi][kf] = *(const bf16x8*)(qkv +
          (size_t)(b * Tt + q0 + qi * 16 + l15) * E3 + h * 64 + kf * 32 + quad * 8);

  f32x4 o[4][4], ol[4];
#pragma unroll
  for (int qi = 0; qi < 4; ++qi) {
    ol[qi] = f32x4{0.f, 0.f, 0.f, 0.f};
#pragma unroll
    for (int di = 0; di < 4; ++di) o[qi][di] = f32x4{0.f, 0.f, 0.f, 0.f};
  }
  bf16x8 ones;
#pragma unroll
  for (int i = 0; i < 8; ++i) ones[i] = (short)0x3F80;  // bf16 1.0

  const unsigned short* kp =
      qkv + (size_t)(b * Tt + kh * 1024 + l15) * E3 + Ee + h * 64 + quad * 8;
  const unsigned short* vp = vt + ((size_t)bh * 64 + l15) * Tt + kh * 1024 + quad * 8;

  bf16x8 kb[4][2], vb[4][2];
#pragma unroll
  for (int ki = 0; ki < 4; ++ki)
#pragma unroll
    for (int kf = 0; kf < 2; ++kf)
      kb[ki][kf] = *(const bf16x8*)(kp + (size_t)ki * 16 * E3 + kf * 32);
#pragma unroll
  for (int di = 0; di < 4; ++di)
#pragma unroll
    for (int kf = 0; kf < 2; ++kf)
      vb[di][kf] = *(const bf16x8*)(vp + di * 16 * Tt + kf * 32);

  auto body = [&](bool reload) __attribute__((always_inline)) {
    // ---- S^T tiles + exp + pack + LDS write; kb[ki] reloaded after last use
#pragma unroll
    for (int ki = 0; ki < 4; ++ki) {
      f32x4 s[4];
#pragma unroll
      for (int qi = 0; qi < 4; ++qi) {
        s[qi] = mfma16(kb[ki][0], qa[qi][0], f32x4{0.f, 0.f, 0.f, 0.f});
        s[qi] = mfma16(kb[ki][1], qa[qi][1], s[qi]);
      }
      if (reload) {
        kb[ki][0] = *(const bf16x8*)(kp + (size_t)ki * 16 * E3);
        kb[ki][1] = *(const bf16x8*)(kp + (size_t)ki * 16 * E3 + 32);
      }
#pragma unroll
      for (int qi = 0; qi < 4; ++qi) {
        const float e0 = __builtin_amdgcn_exp2f(s[qi][0]);
        const float e1 = __builtin_amdgcn_exp2f(s[qi][1]);
        const float e2 = __builtin_amdgcn_exp2f(s[qi][2]);
        const float e3 = __builtin_amdgcn_exp2f(s[qi][3]);
        uint2 w;  // truncate-to-bf16 pairs (bias cancels: denom uses same P)
        w.x = __builtin_amdgcn_perm(__float_as_uint(e1), __float_as_uint(e0), 0x07060302u);
        w.y = __builtin_amdgcn_perm(__float_as_uint(e3), __float_as_uint(e2), 0x07060302u);
        *(uint2*)(ps + (qi * 16 + l15) * 64 + (((ki * 4 + quad) ^ swz) << 2)) = w;
      }
    }

    // ---- P read-back (per-qi, 8 regs live) + ones/PV MFMAs
#pragma unroll
    for (int qi = 0; qi < 4; ++qi) {
      bf16x8 pa0 = *(const bf16x8*)(ps + (qi * 16 + l15) * 64 + (((quad * 2) ^ swz) << 2));
      bf16x8 pa1 = *(const bf16x8*)(ps + (qi * 16 + l15) * 64 + (((8 + quad * 2) ^ swz) << 2));
      ol[qi] = mfma16(pa0, ones, ol[qi]);
      ol[qi] = mfma16(pa1, ones, ol[qi]);
#pragma unroll
      for (int di = 0; di < 4; ++di) {
        o[qi][di] = mfma16(pa0, vb[di][0], o[qi][di]);
        o[qi][di] = mfma16(pa1, vb[di][1], o[qi][di]);
      }
    }
    // ---- vb reload for next iter (after last PV use; WAR-safe)
    if (reload) {
#pragma unroll
      for (int di = 0; di < 4; ++di)
#pragma unroll
        for (int kf = 0; kf < 2; ++kf)
          vb[di][kf] = *(const bf16x8*)(vp + di * 16 * Tt + kf * 32);
    }
  };

  for (int it = 0; it < 15; ++it) {  // 16 x 64 keys = this wave's k-half
    kp += 64 * E3;   // advance FIRST: reloads inside body target the next tile
    vp += 64;
    body(true);
  }
  body(false);       // peeled last iteration: no prefetch, no OOB

  // ---- combine k-halves: odd waves dump (O,l) to LDS; even waves add+store
  __syncthreads();   // all waves done with their P slabs
  f32x4* const ex = (f32x4*)lds + (size_t)pair * 1280;  // 20 slots x 64 lanes
  if (kh == 1) {
#pragma unroll
    for (int qi = 0; qi < 4; ++qi) {
#pragma unroll
      for (int di = 0; di < 4; ++di) ex[(qi * 4 + di) * 64 + lane] = o[qi][di];
      ex[(16 + qi) * 64 + lane] = ol[qi];
    }
  }
  __syncthreads();
  if (kh == 0) {
#pragma unroll
    for (int qi = 0; qi < 4; ++qi) {
      const f32x4 l2 = ex[(16 + qi) * 64 + lane];
      f32x4 inv;
#pragma unroll
      for (int r = 0; r < 4; ++r) inv[r] = 1.0f / (ol[qi][r] + l2[r]);
#pragma unroll
      for (int di = 0; di < 4; ++di) {
        const f32x4 o2 = ex[(qi * 4 + di) * 64 + lane];
#pragma unroll
        for (int r = 0; r < 4; ++r)
          ctx[(size_t)(b * Tt + q0 + qi * 16 + quad * 4 + r) * Ee + h * 64 + di * 16 + l15] =
              f2bf((o[qi][di][r] + o2[r]) * inv[r]);
      }
    }
  }
}

// ---------------------------------------------------------------------------
extern "C" void kernel_launch(void* const* d_in, const int* in_sizes, int n_in,
                              void* d_out, int out_size, void* d_ws, size_t ws_size,
                              hipStream_t stream) {
  const float* query = (const float*)d_in[0];
  const float* in_w  = (const float*)d_in[1];
  const float* in_b  = (const float*)d_in[2];
  const float* out_w = (const float*)d_in[3];
  const float* out_b = (const float*)d_in[4];
  float* out = (float*)d_out;

  char* w = (char*)d_ws;
  unsigned short* qkvb = (unsigned short*)(w);                 // 48 MiB
  unsigned short* ctxb = (unsigned short*)(w + 50331648);      // 16 MiB
  unsigned short* qb   = (unsigned short*)(w + 67108864);      // 16 MiB
  unsigned short* wib  = (unsigned short*)(w + 83886080);      // 6 MiB
  unsigned short* wob  = (unsigned short*)(w + 90177536);      // 2 MiB
  unsigned short* vtb  = (unsigned short*)(w + 92274688);      // 16 MiB

  // 0) all fp32->bf16 conversions in one launch
  cvt_all<<<6144, 256, 0, stream>>>(query, in_w, out_w, qb, wib, wob);
  // 1) qkv = query @ in_w^T + in_b  (q part pre-scaled by log2e/8, bf16)
  gemm_bt<true, true><<<dim3(E3 / 128, Mm / 128), 256, 0, stream>>>(qb, wib, in_b, qkvb, E3, Ee);
  // 1b) pre-transpose V: vt[b][h][d][t]
  transpose_v<<<dim3(Bb * Hh, Tt / 128), 256, 0, stream>>>(qkvb, vtb);
  // 2) fused attention (key-split x2, 4 blocks/CU) -> ctx (bf16, [B,T,E])
  attn_mfma5<<<dim3(Bb * Hh, Tt / 128), 256, 0, stream>>>(qkvb, vtb, ctxb);
  // 3) out = ctx @ out_w^T + out_b  (fp32 out)
  gemm_bt<false, false><<<dim3(Ee / 128, Mm / 128), 256, 0, stream>>>(ctxb, wob, out_b, out, Ee, Ee);
}

// Round 7
// 312.964 us; speedup vs baseline: 1.0402x; 1.0402x over previous
//
#include <hip/hip_runtime.h>
#include <math.h>

using bf16x8 = __attribute__((ext_vector_type(8))) short;
using f32x4  = __attribute__((ext_vector_type(4))) float;
using u16x8  = __attribute__((ext_vector_type(8))) unsigned short;
using u16x4  = __attribute__((ext_vector_type(4))) unsigned short;

constexpr int Bb = 4, Tt = 2048, Ee = 1024, Hh = 16;
constexpr int Mm = Bb * Tt;   // 8192
constexpr int E3 = 3 * Ee;    // 3072

__device__ __forceinline__ unsigned short f2bf(float f) {
  union { float f; unsigned int u; } c; c.f = f;
  unsigned int u = c.u;
  u += 0x7fffu + ((u >> 16) & 1u);   // RNE
  return (unsigned short)(u >> 16);
}

__device__ __forceinline__ f32x4 mfma16(bf16x8 a, bf16x8 b, f32x4 c) {
  return __builtin_amdgcn_mfma_f32_16x16x32_bf16(a, b, c, 0, 0, 0);
}

__device__ __forceinline__ void gload_lds16(const unsigned short* g, unsigned short* l) {
  __builtin_amdgcn_global_load_lds(
      (const __attribute__((address_space(1))) unsigned int*)g,
      (__attribute__((address_space(3))) unsigned int*)l, 16, 0, 0);
}

// ---------------------------------------------------------------------------
// fused fp32 -> bf16 conversion for all three inputs (one launch)
// ---------------------------------------------------------------------------
__global__ void cvt_all(const float* __restrict__ q, const float* __restrict__ iw,
                        const float* __restrict__ ow, unsigned short* __restrict__ qb,
                        unsigned short* __restrict__ wib, unsigned short* __restrict__ wob) {
  constexpr int nQ = Mm * Ee / 8, nI = E3 * Ee / 8, nO = Ee * Ee / 8;
  int i = blockIdx.x * 256 + threadIdx.x;
  const float* in; unsigned short* out;
  if (i < nQ) { in = q; out = qb; }
  else if (i < nQ + nI) { in = iw; out = wib; i -= nQ; }
  else if (i < nQ + nI + nO) { in = ow; out = wob; i -= nQ + nI; }
  else return;
  const float4* p = (const float4*)in + (size_t)i * 2;
  const float4 a = p[0], b = p[1];
  u16x8 r = { f2bf(a.x), f2bf(a.y), f2bf(a.z), f2bf(a.w),
              f2bf(b.x), f2bf(b.y), f2bf(b.z), f2bf(b.w) };
  *(u16x8*)(out + (size_t)i * 8) = r;
}

// ---------------------------------------------------------------------------
// C[M,N] = A[M,K] * Bw[N,K]^T + bias  (bf16 MFMA, m97-style)
// QSCALE: cols<1024 (q part) scaled by log2(e)/8 after bias (exp2 trick).
// ---------------------------------------------------------------------------
template <bool OUT_BF16, bool QSCALE>
__global__ __launch_bounds__(256, 2)
void gemm_bt(const unsigned short* __restrict__ A, const unsigned short* __restrict__ Bw,
             const float* __restrict__ bias, void* __restrict__ Cout, int N, int K) {
  __shared__ alignas(16) unsigned short As[128 * 32];
  __shared__ alignas(16) unsigned short Bs[128 * 32];
  const int tid = threadIdx.x;
  const int wave = tid >> 6, lane = tid & 63;
  const int l15 = lane & 15, quad = lane >> 4;
  const int wr = wave >> 1, wc = wave & 1;
  const int row0 = blockIdx.y * 128, col0 = blockIdx.x * 128;
  const int srow = lane >> 2, sslot = lane & 3;

  f32x4 acc[4][4];
#pragma unroll
  for (int i = 0; i < 4; ++i)
#pragma unroll
    for (int j = 0; j < 4; ++j) acc[i][j] = f32x4{0.f, 0.f, 0.f, 0.f};

  for (int k0 = 0; k0 < K; k0 += 32) {
#pragma unroll
    for (int t = 0; t < 2; ++t) {
      const int rA = wave * 32 + t * 16 + srow;          // 0..127
      const int g = sslot ^ ((rA >> 1) & 3);             // swizzled global chunk
      gload_lds16(A  + (size_t)(row0 + rA) * K + k0 + g * 8, &As[(wave * 32 + t * 16) * 32]);
      gload_lds16(Bw + (size_t)(col0 + rA) * K + k0 + g * 8, &Bs[(wave * 32 + t * 16) * 32]);
    }
    __syncthreads();

    bf16x8 af[4], bfr[4];
#pragma unroll
    for (int mi = 0; mi < 4; ++mi) {
      const int m = wr * 64 + mi * 16 + l15;
      af[mi] = *(const bf16x8*)&As[m * 32 + (quad ^ ((m >> 1) & 3)) * 8];
    }
#pragma unroll
    for (int ni = 0; ni < 4; ++ni) {
      const int n = wc * 64 + ni * 16 + l15;
      bfr[ni] = *(const bf16x8*)&Bs[n * 32 + (quad ^ ((n >> 1) & 3)) * 8];
    }
#pragma unroll
    for (int mi = 0; mi < 4; ++mi)
#pragma unroll
      for (int ni = 0; ni < 4; ++ni) acc[mi][ni] = mfma16(af[mi], bfr[ni], acc[mi][ni]);
    __syncthreads();
  }

#pragma unroll
  for (int mi = 0; mi < 4; ++mi)
#pragma unroll
    for (int ni = 0; ni < 4; ++ni) {
      const int col = col0 + wc * 64 + ni * 16 + l15;
      const float bv = bias[col];
      const float scale = (QSCALE && col < 1024) ? 0.18033688f : 1.0f;  // log2(e)/8
#pragma unroll
      for (int r = 0; r < 4; ++r) {
        const int row = row0 + wr * 64 + mi * 16 + quad * 4 + r;
        float v = (acc[mi][ni][r] + bv) * scale;
        if (OUT_BF16)
          ((unsigned short*)Cout)[(size_t)row * N + col] = f2bf(v);
        else
          ((float*)Cout)[(size_t)row * N + col] = v;
      }
    }
}

// ---------------------------------------------------------------------------
// V transpose: vt[b][h][d][t] <- qkv v-part [b][t][2048 + h*64 + d]
// ---------------------------------------------------------------------------
__global__ __launch_bounds__(256, 2)
void transpose_v(const unsigned short* __restrict__ qkv, unsigned short* __restrict__ vt) {
  __shared__ unsigned short L[128][66];
  const int tid = threadIdx.x;
  const int bh = blockIdx.x, b = bh >> 4, h = bh & 15;
  const int t0 = blockIdx.y * 128;
#pragma unroll
  for (int p = 0; p < 8; ++p) {
    const int tl = p * 16 + (tid >> 4);
    const int d = (tid & 15) * 4;
    *(u16x4*)&L[tl][d] = *(const u16x4*)(qkv + (size_t)(b * Tt + t0 + tl) * E3 + 2 * Ee + h * 64 + d);
  }
  __syncthreads();
#pragma unroll
  for (int p = 0; p < 8; ++p) {
    const int dw = (tid >> 5) * 8 + p;
    const int tw = (tid & 31) * 4;
    u16x4 w = { L[tw][dw], L[tw + 1][dw], L[tw + 2][dw], L[tw + 3][dw] };
    *(u16x4*)(vt + ((size_t)bh * 64 + dw) * Tt + t0 + tw) = w;
  }
}

// ---------------------------------------------------------------------------
// Fused attention, sub-tile software pipeline. Wave = 64 q-rows x 2048 keys,
// barrier-free, per-wave-private LDS P slab (64x64 bf16, XOR-swizzled).
// Key stream processed as 128 sub-tiles of 16 keys. Each sub-step:
//   (A) exp2/pack/ds_write of the PREVIOUS sub-tile's scores  [VALU pipe]
//   (B) S^T MFMAs of the CURRENT sub-tile                     [MFMA pipe]
// -> independent chains, co-issued. PV(j) at each 64-key tile seam, placed
// AFTER the next tile's first S-MFMAs so the LDS write->read wait is covered.
// kb[ki]/vb reloads sit >=4 sub-steps ahead of use. l = P.ones MFMA.
// ---------------------------------------------------------------------------
__global__ __launch_bounds__(256, 2)
void attn_mfma6(const unsigned short* __restrict__ qkv,
                const unsigned short* __restrict__ vt,
                unsigned short* __restrict__ ctx) {
  __shared__ alignas(16) unsigned short Ps[4 * 4096];  // per-wave 64x64 bf16
  const int tid = threadIdx.x;
  const int wave = tid >> 6, lane = tid & 63;
  const int l15 = lane & 15, quad = lane >> 4;
  const int bh = blockIdx.x, b = bh >> 4, h = bh & 15;
  const int q0 = blockIdx.y * 256 + wave * 64;
  unsigned short* const ps = &Ps[wave * 4096];
  const int swz = l15 & 14;

  // Q fragments (B operand): q = q0 + qi*16 + l15, d = kf*32 + quad*8
  bf16x8 qa[4][2];
#pragma unroll
  for (int qi = 0; qi < 4; ++qi)
#pragma unroll
    for (int kf = 0; kf < 2; ++kf)
      qa[qi][kf] = *(const bf16x8*)(qkv +
          (size_t)(b * Tt + q0 + qi * 16 + l15) * E3 + h * 64 + kf * 32 + quad * 8);

  f32x4 o[4][4], ol[4];
#pragma unroll
  for (int qi = 0; qi < 4; ++qi) {
    ol[qi] = f32x4{0.f, 0.f, 0.f, 0.f};
#pragma unroll
    for (int di = 0; di < 4; ++di) o[qi][di] = f32x4{0.f, 0.f, 0.f, 0.f};
  }
  bf16x8 ones;
#pragma unroll
  for (int i = 0; i < 8; ++i) ones[i] = (short)0x3F80;  // bf16 1.0

  const unsigned short* kp = qkv + (size_t)(b * Tt + l15) * E3 + Ee + h * 64 + quad * 8;
  const unsigned short* vp = vt + ((size_t)bh * 64 + l15) * Tt + quad * 8;

  bf16x8 kb[4][2], vb[4][2];
#pragma unroll
  for (int ki = 0; ki < 4; ++ki)
#pragma unroll
    for (int kf = 0; kf < 2; ++kf)
      kb[ki][kf] = *(const bf16x8*)(kp + (size_t)ki * 16 * E3 + kf * 32);
#pragma unroll
  for (int di = 0; di < 4; ++di)
#pragma unroll
    for (int kf = 0; kf < 2; ++kf)
      vb[di][kf] = *(const bf16x8*)(vp + di * 16 * Tt + kf * 32);
  kp += 64 * E3;   // -> tile 1 (reload source)
  vp += 64;        // -> tile 1 (next vb reload)

  f32x4 sp[4], sn[4];

  // exp/pack/write previous sub-tile scores into slot (0..3) of the P slab
  auto expwrite = [&](int slot) __attribute__((always_inline)) {
#pragma unroll
    for (int qi = 0; qi < 4; ++qi) {
      const float e0 = __builtin_amdgcn_exp2f(sp[qi][0]);
      const float e1 = __builtin_amdgcn_exp2f(sp[qi][1]);
      const float e2 = __builtin_amdgcn_exp2f(sp[qi][2]);
      const float e3 = __builtin_amdgcn_exp2f(sp[qi][3]);
      uint2 w;  // truncate-to-bf16 pairs (bias cancels: denom uses same P)
      w.x = __builtin_amdgcn_perm(__float_as_uint(e1), __float_as_uint(e0), 0x07060302u);
      w.y = __builtin_amdgcn_perm(__float_as_uint(e3), __float_as_uint(e2), 0x07060302u);
      *(uint2*)(ps + (qi * 16 + l15) * 64 + (((slot * 4 + quad) ^ swz) << 2)) = w;
    }
  };
  // S^T MFMAs for current sub-tile (kb row ki)
  auto Sstep = [&](int ki) __attribute__((always_inline)) {
#pragma unroll
    for (int qi = 0; qi < 4; ++qi) {
      sn[qi] = mfma16(kb[ki][0], qa[qi][0], f32x4{0.f, 0.f, 0.f, 0.f});
      sn[qi] = mfma16(kb[ki][1], qa[qi][1], sn[qi]);
    }
  };
  auto copy_sp = [&]() __attribute__((always_inline)) {
#pragma unroll
    for (int qi = 0; qi < 4; ++qi) sp[qi] = sn[qi];
  };
  // PV for the tile whose P slab is complete; optional vb reload (next tile)
  auto pvstep = [&](bool reload_vb) __attribute__((always_inline)) {
#pragma unroll
    for (int qi = 0; qi < 4; ++qi) {
      bf16x8 pa0 = *(const bf16x8*)(ps + (qi * 16 + l15) * 64 + (((quad * 2) ^ swz) << 2));
      bf16x8 pa1 = *(const bf16x8*)(ps + (qi * 16 + l15) * 64 + (((8 + quad * 2) ^ swz) << 2));
      ol[qi] = mfma16(pa0, ones, ol[qi]);
      ol[qi] = mfma16(pa1, ones, ol[qi]);
#pragma unroll
      for (int di = 0; di < 4; ++di) {
        o[qi][di] = mfma16(pa0, vb[di][0], o[qi][di]);
        o[qi][di] = mfma16(pa1, vb[di][1], o[qi][di]);
      }
    }
    if (reload_vb) {
#pragma unroll
      for (int di = 0; di < 4; ++di)
#pragma unroll
        for (int kf = 0; kf < 2; ++kf)
          vb[di][kf] = *(const bf16x8*)(vp + di * 16 * Tt + kf * 32);
      vp += 64;
    }
  };

  // prologue: S(0,0); kb[0] -> tile 1
  Sstep(0); copy_sp();
  kb[0][0] = *(const bf16x8*)(kp);
  kb[0][1] = *(const bf16x8*)(kp + 32);

  for (int j = 0; j < 31; ++j) {
    // (j,1)
    expwrite(0);                       // slot (j,0)
    Sstep(1);
    kb[1][0] = *(const bf16x8*)(kp + (size_t)16 * E3);
    kb[1][1] = *(const bf16x8*)(kp + (size_t)16 * E3 + 32);
    copy_sp();
    // (j,2)
    expwrite(1);
    Sstep(2);
    kb[2][0] = *(const bf16x8*)(kp + (size_t)32 * E3);
    kb[2][1] = *(const bf16x8*)(kp + (size_t)32 * E3 + 32);
    copy_sp();
    // (j,3)
    expwrite(2);
    Sstep(3);
    kb[3][0] = *(const bf16x8*)(kp + (size_t)48 * E3);
    kb[3][1] = *(const bf16x8*)(kp + (size_t)48 * E3 + 32);
    kp += 64 * E3;                     // -> tile j+2
    copy_sp();
    // seam: (j+1,0) then PV(j)
    expwrite(3);                       // completes P(j)
    Sstep(0);                          // S(j+1,0): MFMA cover for the LDS wait
    if (j < 30) {
      kb[0][0] = *(const bf16x8*)(kp);
      kb[0][1] = *(const bf16x8*)(kp + 32);
    }
    copy_sp();
    pvstep(true);                      // PV(j); vb -> tile j+1
  }
  // tail: tile 31 (sp holds (31,0))
  expwrite(0); Sstep(1); copy_sp();
  expwrite(1); Sstep(2); copy_sp();
  expwrite(2); Sstep(3); copy_sp();
  expwrite(3);
  pvstep(false);                       // PV(31)

  // epilogue: divide by l (same layout), store bf16 ctx
#pragma unroll
  for (int qi = 0; qi < 4; ++qi) {
    f32x4 inv;
#pragma unroll
    for (int r = 0; r < 4; ++r) inv[r] = 1.0f / ol[qi][r];
#pragma unroll
    for (int di = 0; di < 4; ++di)
#pragma unroll
      for (int r = 0; r < 4; ++r)
        ctx[(size_t)(b * Tt + q0 + qi * 16 + quad * 4 + r) * Ee + h * 64 + di * 16 + l15] =
            f2bf(o[qi][di][r] * inv[r]);
  }
}

// ---------------------------------------------------------------------------
extern "C" void kernel_launch(void* const* d_in, const int* in_sizes, int n_in,
                              void* d_out, int out_size, void* d_ws, size_t ws_size,
                              hipStream_t stream) {
  const float* query = (const float*)d_in[0];
  const float* in_w  = (const float*)d_in[1];
  const float* in_b  = (const float*)d_in[2];
  const float* out_w = (const float*)d_in[3];
  const float* out_b = (const float*)d_in[4];
  float* out = (float*)d_out;

  char* w = (char*)d_ws;
  unsigned short* qkvb = (unsigned short*)(w);                 // 48 MiB
  unsigned short* ctxb = (unsigned short*)(w + 50331648);      // 16 MiB
  unsigned short* qb   = (unsigned short*)(w + 67108864);      // 16 MiB
  unsigned short* wib  = (unsigned short*)(w + 83886080);      // 6 MiB
  unsigned short* wob  = (unsigned short*)(w + 90177536);      // 2 MiB
  unsigned short* vtb  = (unsigned short*)(w + 92274688);      // 16 MiB

  // 0) all fp32->bf16 conversions in one launch
  cvt_all<<<6144, 256, 0, stream>>>(query, in_w, out_w, qb, wib, wob);
  // 1) qkv = query @ in_w^T + in_b  (q part pre-scaled by log2e/8, bf16)
  gemm_bt<true, true><<<dim3(E3 / 128, Mm / 128), 256, 0, stream>>>(qb, wib, in_b, qkvb, E3, Ee);
  // 1b) pre-transpose V: vt[b][h][d][t]
  transpose_v<<<dim3(Bb * Hh, Tt / 128), 256, 0, stream>>>(qkvb, vtb);
  // 2) fused attention (sub-tile pipelined) -> ctx (bf16, [B,T,E])
  attn_mfma6<<<dim3(Bb * Hh, Tt / 256), 256, 0, stream>>>(qkvb, vtb, ctxb);
  // 3) out = ctx @ out_w^T + out_b  (fp32 out)
  gemm_bt<false, false><<<dim3(Ee / 128, Mm / 128), 256, 0, stream>>>(ctxb, wob, out_b, out, Ee, Ee);
}